// Round 12
// baseline (141.671 us; speedup 1.0000x reference)
//
#include <hip/hip_runtime.h>

// B=2, C=3, H=W=1024. fp32 in/out. Ladder: R9 194us (latency-bound) ->
// R11 LDS-tile 80us (VALU 62%, SQ_LDS_BANK_CONFLICT ~41% of cycles,
// 20 ds_read_b32 per sample point). R12: interleaved LDS layout —
// x-planes as float4 (ds_read_b128 per corner), tangent as float2
// (ds_read_b64 per corner): 20 -> 8 LDS reads per sample point, fewer
// address calcs, fewer conflict events. Arithmetic untouched => bit-identical.
constexpr int Bb = 2, Cc = 3, Hh = 1024, Ww = 1024;
constexpr int HWp = Hh * Ww;
constexpr int N_STEPS = 4;
constexpr int TS = 16;                  // pixels per tile side
constexpr int HALO = 6;                 // max drift 4px + margin
constexpr int TD = TS + 2 * HALO;       // 28
constexpr int TSTR = TD + 1;            // 29 (odd stride)
constexpr int TILE_N = (TD - 1) * TSTR + TD;   // 810+1 slots needed

struct Corn { int o00, o01, o10, o11; float wx, wy; };

// positions -> bilinear corners (tile-local slot indices). Arithmetic on
// fx/fy/wx/wy is IDENTICAL to the numpy golden (contract off).
__device__ __forceinline__ Corn mkcorn(float px, float py, int ox, int oy) {
#pragma clang fp contract(off)
    float fx = px * 1024.0f - 0.5f;     // *1024 exact (pow2); -0.5 rounds once
    float fy = py * 1024.0f - 0.5f;
    float fx0 = floorf(fx), fy0 = floorf(fy);
    Corn c;
    c.wx = fx - fx0;
    c.wy = fy - fy0;
    int x0 = (int)fx0, y0 = (int)fy0;
    int x0i = min(max(x0, 0), Ww - 1);  // global border clamp
    int x1i = min(x0i + 1, Ww - 1);
    int y0i = min(max(y0, 0), Hh - 1);
    int y1i = min(y0i + 1, Hh - 1);
    int lx0 = min(max(x0i - ox, 0), TD - 1);   // defensive tile clamp
    int lx1 = min(max(x1i - ox, 0), TD - 1);
    int ly0 = min(max(y0i - oy, 0), TD - 1);
    int ly1 = min(max(y1i - oy, 0), TD - 1);
    c.o00 = ly0 * TSTR + lx0; c.o01 = ly0 * TSTR + lx1;
    c.o10 = ly1 * TSTR + lx0; c.o11 = ly1 * TSTR + lx1;
    return c;
}

__global__ __launch_bounds__(256) void flow_smooth_kernel(
    const float* __restrict__ x,
    const float* __restrict__ tg,
    const float* __restrict__ sg,
    float* __restrict__ out)
{
#pragma clang fp contract(off)
    __shared__ float4 xl[TILE_N];       // 3 x-channels + pad : 13.0 KB
    __shared__ float2 tl[TILE_N];       // tangent x,y        : 6.5 KB

    const int tx0 = blockIdx.x * TS, ty0 = blockIdx.y * TS;
    const int b = blockIdx.z;
    const int tid = threadIdx.x;        // 0..255

    const float* xp  = x  + (size_t)b * Cc * HWp;
    const float* txp = tg + (size_t)b * 2 * HWp;
    const float* typ = txp + HWp;

    const int ox = tx0 - HALO, oy = ty0 - HALO;

    // ---- stage 28x28 (border-clamped): 5 global b32 loads -> 2 LDS writes
    for (int e = tid; e < TD * TD; e += 256) {
        int r = e / TD, cc = e - r * TD;
        int gy = min(max(oy + r, 0), Hh - 1);
        int gx = min(max(ox + cc, 0), Ww - 1);
        int g = gy * Ww + gx;
        float4 v; v.x = xp[g]; v.y = xp[g + HWp]; v.z = xp[g + 2 * HWp]; v.w = 0.f;
        float2 t; t.x = txp[g]; t.y = typ[g];
        int slot = r * TSTR + cc;
        xl[slot] = v;
        tl[slot] = t;
    }
    __syncthreads();

    // ---- per-pixel march (all gathers via b128/b64 LDS reads)
    const int lx = tid & (TS - 1), ly = tid >> 4;
    const int j = tx0 + lx, i = ty0 + ly;
    const int ctr = (HALO + ly) * TSTR + (HALO + lx);

    float sig = sg[b];
    float half_width = 2.0f * sig;
    float two_sigma2 = (2.0f * sig) * sig;
    const float stepf = (float)(1.0 / 0.3333);

    float ks[N_STEPS];
#pragma unroll
    for (int it = 0; it < N_STEPS; ++it) {
        float r = ((float)it + 1.0f) * stepf;
        float k = expf(-(r * r) / two_sigma2);
        ks[it] = (r < half_width) ? k : 0.0f;
    }

    const float inv1024 = 1.0f / 1024.0f;
    const float psx = ((float)j + 0.5f) * inv1024;
    const float psy = ((float)i + 0.5f) * inv1024;

    const float2 tc = tl[ctr];
    const float v0x = tc.x, v0y = tc.y;

    float c1a = 0.f, c1b = 0.f, c1c = 0.f, s1 = 0.f;
    float c2a = 0.f, c2b = 0.f, c2c = 0.f, s2 = 0.f;

#pragma unroll
    for (int d = 0; d < 2; ++d) {
        float vx = d ? -v0x : v0x;
        float vy = d ? -v0y : v0y;
        float px = psx + vx * inv1024;  // p0 = p_start + v0/tex
        float py = psy + vy * inv1024;
        float a0 = 0.f, a1 = 0.f, a2 = 0.f, as = 0.f;
#pragma unroll
        for (int it = 0; it < N_STEPS; ++it) {
            Corn c = mkcorn(px, py, ox, oy);
            bool inb = (px >= 0.0f) && (px < 1.0f) && (py >= 0.0f) && (py < 1.0f);
            float w = inb ? ks[it] : 0.0f;        // +0 / *0: bit-exact no-op
            float omx = 1.0f - c.wx, omy = 1.0f - c.wy;
            {   // x bilinear, 3 channels from 4 b128 reads (same numpy order)
                float4 v00 = xl[c.o00], v01 = xl[c.o01];
                float4 v10 = xl[c.o10], v11 = xl[c.o11];
                float t0 = v00.x * omx + v01.x * c.wx;
                float b0 = v10.x * omx + v11.x * c.wx;
                float t1 = v00.y * omx + v01.y * c.wx;
                float b1 = v10.y * omx + v11.y * c.wx;
                float t2 = v00.z * omx + v01.z * c.wx;
                float b2 = v10.z * omx + v11.z * c.wx;
                a0 += (t0 * omy + b0 * c.wy) * w;
                a1 += (t1 * omy + b1 * c.wy) * w;
                a2 += (t2 * omy + b2 * c.wy) * w;
                as += w;
            }
            if (it == N_STEPS - 1) break;         // ref discards final advance
            {   // tangent bilinear from 4 b64 reads
                float2 v00 = tl[c.o00], v01 = tl[c.o01];
                float2 v10 = tl[c.o10], v11 = tl[c.o11];
                float tt = v00.x * omx + v01.x * c.wx;
                float bb = v10.x * omx + v11.x * c.wx;
                float tfx = tt * omy + bb * c.wy;
                tt = v00.y * omx + v01.y * c.wx;
                bb = v10.y * omx + v11.y * c.wx;
                float tfy = tt * omy + bb * c.wy;
                float vt = (vx * tfx) + (vy * tfy);
                if (vt < 0.0f) { tfx = -tfx; tfy = -tfy; }   // exact negation
                px = px + tfx * inv1024;
                py = py + tfy * inv1024;
                vx = tfx; vy = tfy;
            }
        }
        if (d == 0) { c1a = a0; c1b = a1; c1c = a2; s1 = as; }
        else        { c2a = a0; c2b = a1; c2c = a2; s2 = as; }
    }

    const int pix = i * Ww + j;
    const float4 xc = xl[ctr];
    float denom = (1.0f + s1) + s2;
    float* op = out + (size_t)b * Cc * HWp;
    op[pix]           = ((xc.x + c1a) + c2a) / denom;
    op[pix + HWp]     = ((xc.y + c1b) + c2b) / denom;
    op[pix + 2 * HWp] = ((xc.z + c1c) + c2c) / denom;
}

extern "C" void kernel_launch(void* const* d_in, const int* in_sizes, int n_in,
                              void* d_out, int out_size, void* d_ws, size_t ws_size,
                              hipStream_t stream) {
    const float* x = nullptr; const float* tg = nullptr; const float* sg = nullptr;
    for (int t = 0; t < n_in; ++t) {
        if (in_sizes[t] == Bb * Cc * HWp)      x  = (const float*)d_in[t];
        else if (in_sizes[t] == Bb * 2 * HWp)  tg = (const float*)d_in[t];
        else                                   sg = (const float*)d_in[t];
    }
    float* out = (float*)d_out;

    dim3 block(256, 1, 1);
    dim3 grid(Ww / TS, Hh / TS, Bb);   // 64 x 64 x 2 = 8192 blocks
    flow_smooth_kernel<<<grid, block, 0, stream>>>(x, tg, sg, out);
}

// Round 13
// 140.421 us; speedup vs baseline: 1.0089x; 1.0089x over previous
//
#include <hip/hip_runtime.h>

// B=2, C=3, H=W=1024. fp32 in/out. Ladder: R9 194us latency-bound ->
// R11 LDS-tile 80us -> R12 b128/b64 LDS layout 71us (VALU-issue-bound:
// VALUBusy 77%). R13: VALU slim — march in PIXEL UNITS (q = p*1024; exact
// pow2 scale commutes with fp rounding => bit-exact vs numpy), drop
// defensive tile clamps (corners proven within halo), and skip global
// border clamps on interior tiles (wave-uniform edge branch).
constexpr int Bb = 2, Cc = 3, Hh = 1024, Ww = 1024;
constexpr int HWp = Hh * Ww;
constexpr int N_STEPS = 4;
constexpr int TS = 16;                  // pixels per tile side
constexpr int HALO = 6;                 // max drift 4px + corner 1 + margin
constexpr int TD = TS + 2 * HALO;       // 28
constexpr int TSTR = TD + 1;            // 29 (odd stride)
constexpr int TILE_N = (TD - 1) * TSTR + TD + 1;

struct Corn { int o00, o01, o10, o11; float wx, wy; };

// q-space corners: fx = qx - 0.5 equals ref's fl(fl(px*1024) - 0.5) since
// px*1024 is exact. wx/wy identical to numpy golden (contract off).
__device__ __forceinline__ Corn mkcorn(float qx, float qy, int ox, int oy, bool edge) {
#pragma clang fp contract(off)
    float fx = qx - 0.5f;
    float fy = qy - 0.5f;
    float fx0 = floorf(fx), fy0 = floorf(fy);
    Corn c;
    c.wx = fx - fx0;
    c.wy = fy - fy0;
    int x0 = (int)fx0, y0 = (int)fy0;
    if (edge) {            // border tiles: replicate ref's border clamp
        int x0i = min(max(x0, 0), Ww - 1);
        int x1i = min(x0i + 1, Ww - 1);
        int y0i = min(max(y0, 0), Hh - 1);
        int y1i = min(y0i + 1, Hh - 1);
        int lx0 = x0i - ox, lx1 = x1i - ox;
        int ly0 = y0i - oy, ly1 = y1i - oy;
        c.o00 = ly0 * TSTR + lx0; c.o01 = ly0 * TSTR + lx1;
        c.o10 = ly1 * TSTR + lx0; c.o11 = ly1 * TSTR + lx1;
    } else {               // interior: clamp provably inactive
        int lx0 = x0 - ox, ly0 = y0 - oy;
        c.o00 = ly0 * TSTR + lx0;
        c.o01 = c.o00 + 1;
        c.o10 = c.o00 + TSTR;
        c.o11 = c.o00 + TSTR + 1;
    }
    return c;
}

__global__ __launch_bounds__(256) void flow_smooth_kernel(
    const float* __restrict__ x,
    const float* __restrict__ tg,
    const float* __restrict__ sg,
    float* __restrict__ out)
{
#pragma clang fp contract(off)
    __shared__ float4 xl[TILE_N];       // x0,x1,x2,(pad)
    __shared__ float2 tl[TILE_N];       // tangent x,y

    const int tx0 = blockIdx.x * TS, ty0 = blockIdx.y * TS;
    const int b = blockIdx.z;
    const int tid = threadIdx.x;        // 0..255
    const bool edge = (blockIdx.x == 0) | (blockIdx.x == gridDim.x - 1) |
                      (blockIdx.y == 0) | (blockIdx.y == gridDim.y - 1);

    const float* xp  = x  + (size_t)b * Cc * HWp;
    const float* txp = tg + (size_t)b * 2 * HWp;
    const float* typ = txp + HWp;

    const int ox = tx0 - HALO, oy = ty0 - HALO;

    // ---- stage 28x28 (border-clamped) tile
    for (int e = tid; e < TD * TD; e += 256) {
        int r = e / TD, cc = e - r * TD;
        int gy = min(max(oy + r, 0), Hh - 1);
        int gx = min(max(ox + cc, 0), Ww - 1);
        int g = gy * Ww + gx;
        float4 v; v.x = xp[g]; v.y = xp[g + HWp]; v.z = xp[g + 2 * HWp]; v.w = 0.f;
        float2 t; t.x = txp[g]; t.y = typ[g];
        int slot = r * TSTR + cc;
        xl[slot] = v;
        tl[slot] = t;
    }
    __syncthreads();

    // ---- per-pixel march, positions in PIXEL units (q = p*1024)
    const int lx = tid & (TS - 1), ly = tid >> 4;
    const int j = tx0 + lx, i = ty0 + ly;
    const int ctr = (HALO + ly) * TSTR + (HALO + lx);

    float sig = sg[b];
    float half_width = 2.0f * sig;
    float two_sigma2 = (2.0f * sig) * sig;
    const float stepf = (float)(1.0 / 0.3333);

    float ks[N_STEPS];
#pragma unroll
    for (int it = 0; it < N_STEPS; ++it) {
        float r = ((float)it + 1.0f) * stepf;
        float k = expf(-(r * r) / two_sigma2);
        ks[it] = (r < half_width) ? k : 0.0f;
    }

    const float qsx = (float)j + 0.5f;   // p_start*1024, exact
    const float qsy = (float)i + 0.5f;

    const float2 tc = tl[ctr];
    const float v0x = tc.x, v0y = tc.y;

    float c1a = 0.f, c1b = 0.f, c1c = 0.f, s1 = 0.f;
    float c2a = 0.f, c2b = 0.f, c2c = 0.f, s2 = 0.f;

#pragma unroll
    for (int d = 0; d < 2; ++d) {
        float vx = d ? -v0x : v0x;
        float vy = d ? -v0y : v0y;
        float qx = qsx + vx;             // == (p_start + v0/tex)*1024 bit-exact
        float qy = qsy + vy;
        float a0 = 0.f, a1 = 0.f, a2 = 0.f, as = 0.f;
#pragma unroll
        for (int it = 0; it < N_STEPS; ++it) {
            Corn c = mkcorn(qx, qy, ox, oy, edge);
            bool inb = (qx >= 0.0f) && (qx < 1024.0f) &&
                       (qy >= 0.0f) && (qy < 1024.0f);
            float w = inb ? ks[it] : 0.0f;        // +0 / *0: bit-exact no-op
            float omx = 1.0f - c.wx, omy = 1.0f - c.wy;
            {   // x bilinear, 3 channels from 4 b128 reads (numpy op order)
                float4 v00 = xl[c.o00], v01 = xl[c.o01];
                float4 v10 = xl[c.o10], v11 = xl[c.o11];
                float t0 = v00.x * omx + v01.x * c.wx;
                float b0 = v10.x * omx + v11.x * c.wx;
                float t1 = v00.y * omx + v01.y * c.wx;
                float b1 = v10.y * omx + v11.y * c.wx;
                float t2 = v00.z * omx + v01.z * c.wx;
                float b2 = v10.z * omx + v11.z * c.wx;
                a0 += (t0 * omy + b0 * c.wy) * w;
                a1 += (t1 * omy + b1 * c.wy) * w;
                a2 += (t2 * omy + b2 * c.wy) * w;
                as += w;
            }
            if (it == N_STEPS - 1) break;         // ref discards final advance
            {   // tangent bilinear from 4 b64 reads
                float2 v00 = tl[c.o00], v01 = tl[c.o01];
                float2 v10 = tl[c.o10], v11 = tl[c.o11];
                float tt = v00.x * omx + v01.x * c.wx;
                float bb = v10.x * omx + v11.x * c.wx;
                float tfx = tt * omy + bb * c.wy;
                tt = v00.y * omx + v01.y * c.wx;
                bb = v10.y * omx + v11.y * c.wx;
                float tfy = tt * omy + bb * c.wy;
                float vt = (vx * tfx) + (vy * tfy);
                if (vt < 0.0f) { tfx = -tfx; tfy = -tfy; }   // exact negation
                qx = qx + tfx;           // == (p + tf/tex)*1024 bit-exact
                qy = qy + tfy;
                vx = tfx; vy = tfy;
            }
        }
        if (d == 0) { c1a = a0; c1b = a1; c1c = a2; s1 = as; }
        else        { c2a = a0; c2b = a1; c2c = a2; s2 = as; }
    }

    const int pix = i * Ww + j;
    const float4 xc = xl[ctr];
    float denom = (1.0f + s1) + s2;
    float* op = out + (size_t)b * Cc * HWp;
    op[pix]           = ((xc.x + c1a) + c2a) / denom;
    op[pix + HWp]     = ((xc.y + c1b) + c2b) / denom;
    op[pix + 2 * HWp] = ((xc.z + c1c) + c2c) / denom;
}

extern "C" void kernel_launch(void* const* d_in, const int* in_sizes, int n_in,
                              void* d_out, int out_size, void* d_ws, size_t ws_size,
                              hipStream_t stream) {
    const float* x = nullptr; const float* tg = nullptr; const float* sg = nullptr;
    for (int t = 0; t < n_in; ++t) {
        if (in_sizes[t] == Bb * Cc * HWp)      x  = (const float*)d_in[t];
        else if (in_sizes[t] == Bb * 2 * HWp)  tg = (const float*)d_in[t];
        else                                   sg = (const float*)d_in[t];
    }
    float* out = (float*)d_out;

    dim3 block(256, 1, 1);
    dim3 grid(Ww / TS, Hh / TS, Bb);   // 64 x 64 x 2 = 8192 blocks
    flow_smooth_kernel<<<grid, block, 0, stream>>>(x, tg, sg, out);
}